// Round 6
// baseline (1542.447 us; speedup 1.0000x reference)
//
#include <hip/hip_runtime.h>
#include <hip/hip_bf16.h>
#include <cstdint>
#include <cstddef>

using bf16    = __bf16;
using bf16x8  = __attribute__((ext_vector_type(8))) __bf16;
using floatx4 = __attribute__((ext_vector_type(4))) float;

// Packet layout (all bf16 GEMM operands):
//   packet = 1024B = one (16-row x 32-k) block of row-major [R x K]
//   packet index = (row>>4)*(K>>5) + (k>>5)
//   element (row,k) at packet*512 + (((k>>3)&3)*16 + (row&15))*8 + (k&7)
// One global_load_lds(16B) per wave moves one packet; one ds_read_b128 per
// lane yields a full 16x32 MFMA fragment. Conflict-free both ways.
//
// ALGEBRA: xv = x*mv + (1-mv)*xx  =>  xv@Wv^T = x@(mv.*Wv)^T + bias_v.
// Both GEMMs of the v/r pair share A = bf16(x); mix folds into the weights.
// Bias partials [16][C] from prep3, summed in gemm_vr7 epilogue.
//
// SCHEDULE (v7): TLP instead of deeper ILP.  Rounds 2-5 post-mortem: with a
// 128 KiB ring only ONE block/CU fits; all 8 resident waves share one
// barrier group, so each slice's DS burst + vmcnt drain + barrier is a
// serial section nothing can hide (MfmaUtil pinned 40-47% across four
// schedule variants; fenced prefetch spilled at the 128-VGPR cap).
// v7: 2-slot ring (64 KiB) + __launch_bounds__(512,4) -> TWO independent
// blocks/CU; one block's MFMA window covers the other's drain (m114
// co-scheduling).  Per slice: stage q+1 into other slot, 12 ds_reads,
// 32 MFMA, vmcnt(0), barrier.
//   WAR: slot (q+1)&1 was last READ during slice q-1, all reads complete
//        before q-1's closing barrier; stage issues after it.  RAW:
//        vmcnt(0)+barrier at end of q -> slot q+1 ready for slice q+1.

__device__ __forceinline__ void async_cp16(const bf16* g, bf16* l) {
    __builtin_amdgcn_global_load_lds(
        (__attribute__((address_space(1))) void*)const_cast<bf16*>(g),
        (__attribute__((address_space(3))) void*)l,
        16, 0, 0);
}

template <int VM>
__device__ __forceinline__ void wait_vm() {
    if constexpr (VM == 8)      asm volatile("s_waitcnt vmcnt(8)" ::: "memory");
    else if constexpr (VM == 4) asm volatile("s_waitcnt vmcnt(4)" ::: "memory");
    else if constexpr (VM == 0) asm volatile("s_waitcnt vmcnt(0)" ::: "memory");
}

__device__ __forceinline__ void barrier_pin() {
    __builtin_amdgcn_s_barrier();
    __builtin_amdgcn_sched_barrier(0);
}

// ---------------------------------------------------------------------------
// prep3: yb < prepRows -> bf16(x) packets; else weight fold+convert:
//   wv' = mv.*Wv, wr' = mr.*Wr, wo' = Wo; bias partials [16][C] per array.
// ---------------------------------------------------------------------------
__global__ __launch_bounds__(256) void prep3(
    const float* __restrict__ x, const float* __restrict__ tmv,
    const float* __restrict__ tmr, const float* __restrict__ xxp,
    const float* __restrict__ wv, const float* __restrict__ wr,
    const float* __restrict__ wo, bf16* __restrict__ xb,
    bf16* __restrict__ wvb, bf16* __restrict__ wrb, bf16* __restrict__ wob,
    float* __restrict__ pV, float* __restrict__ pR,
    int C, int prepRows) {
    __shared__ float red[4][16];
    const int t  = threadIdx.x;
    const int p  = t >> 6, l = t & 63;
    const int c0 = blockIdx.x << 7;
    const int k  = c0 + (p << 5) + ((l >> 4) << 3);
    const int yb = blockIdx.y;
    const int C4 = C >> 4;

    if (yb < prepRows) {
        const int row = (yb << 4) + (l & 15);
        const float4* xi = (const float4*)&x[(size_t)row * C + k];
        const float4 a0 = xi[0], a1 = xi[1];
        const float xa[8] = {a0.x, a0.y, a0.z, a0.w, a1.x, a1.y, a1.z, a1.w};
        bf16x8 ov;
#pragma unroll
        for (int u = 0; u < 8; ++u) ov[u] = (bf16)xa[u];
        const size_t off = ((size_t)yb * (C >> 5) + (c0 >> 5) + p) * 512 + l * 8;
        *(bf16x8*)&xb[off] = ov;
    } else {
        int z = yb - prepRows;
        const float* wsrc; bf16* wdst; const float* sv = nullptr;
        float* bdst = nullptr; int mix = 1;
        if (z < C4)          { wsrc = wv; wdst = wvb; sv = tmv; bdst = pV; }
        else if (z < 2 * C4) { wsrc = wr; wdst = wrb; sv = tmr; bdst = pR; z -= C4; }
        else                 { wsrc = wo; wdst = wob; mix = 0; z -= 2 * C4; }
        const int row = (z << 4) + (l & 15);
        const float4* wi = (const float4*)&wsrc[(size_t)row * C + k];
        const float4 b0 = wi[0], b1 = wi[1];
        const float wa[8] = {b0.x, b0.y, b0.z, b0.w, b1.x, b1.y, b1.z, b1.w};
        bf16x8 ov;
        if (mix) {
            const float4 s0 = *(const float4*)&sv[k],  s1 = *(const float4*)&sv[k + 4];
            const float4 q0 = *(const float4*)&xxp[k], q1 = *(const float4*)&xxp[k + 4];
            const float sa[8] = {s0.x, s0.y, s0.z, s0.w, s1.x, s1.y, s1.z, s1.w};
            const float qa[8] = {q0.x, q0.y, q0.z, q0.w, q1.x, q1.y, q1.z, q1.w};
            float part = 0.f;
#pragma unroll
            for (int u = 0; u < 8; ++u) {
                part += (1.0f - sa[u]) * qa[u] * wa[u];
                ov[u] = (bf16)(wa[u] * sa[u]);
            }
            part += __shfl_xor(part, 16);
            part += __shfl_xor(part, 32);
            if (l < 16) red[p][l] = part;
            __syncthreads();
            if (t < 16) {
                const float s = red[0][t] + red[1][t] + red[2][t] + red[3][t];
                bdst[(size_t)(c0 >> 7) * C + (z << 4) + t] = s;
            }
        } else {
#pragma unroll
            for (int u = 0; u < 8; ++u) ov[u] = (bf16)wa[u];
        }
        const size_t off = ((size_t)z * (C >> 5) + (c0 >> 5) + p) * 512 + l * 8;
        *(bf16x8*)&wdst[off] = ov;
    }
}

// ---------------------------------------------------------------------------
// gemm_vr7: shared-A dual GEMM, BM=256 BN=128, 2-slot ring, 2 blocks/CU.
// LDS slot (16384 elems): X packets [0,16)*512, WV [16,24)*512, WR [24,32)*512.
// Waves 0-3 stage X, 4-5 WV, 6-7 WR.
// ---------------------------------------------------------------------------
__global__ __launch_bounds__(512, 4) void gemm_vr7(
    const bf16* __restrict__ XB, const bf16* __restrict__ WVB,
    const bf16* __restrict__ WRB, const float* __restrict__ pV,
    const float* __restrict__ pR, bf16* __restrict__ RW,
    int M, int N, int K) {
    __shared__ __align__(16) bf16 lds[32768];   // 64 KiB, 2 x 32KB slots

    const int bid    = blockIdx.x;
    const int xcd    = bid & 7;
    const int tt     = bid >> 3;
    const int mtPerX = (M >> 8) >> 3;            // 4
    const int mt     = xcd * mtPerX + (tt % mtPerX);
    const int nt     = tt / mtPerX;
    const int m0     = mt << 8;
    const int n0     = nt << 7;

    const int tid  = threadIdx.x;
    const int wave = tid >> 6;
    const int lane = tid & 63;
    const int quad = lane >> 4;
    const int l16  = lane & 15;
    const int wm   = (wave >> 2) << 7;           // 0 / 128
    const int wn   = (wave & 3) << 5;            // 0,32,64,96
    const int xrb  = (wave >> 2) << 3;
    const int wjb  = (wave & 3) << 1;
    const int KS   = K >> 5;
    const int Q    = K >> 5;

    const bf16* gsrc;
    int grb, ldsOff;
    if (wave < 4)      { gsrc = XB;  grb = (m0 >> 4) + wave * 4;       ldsOff = wave * 2048; }
    else if (wave < 6) { gsrc = WVB; grb = (n0 >> 4) + (wave - 4) * 4; ldsOff = 8192 + (wave - 4) * 2048; }
    else               { gsrc = WRB; grb = (n0 >> 4) + (wave - 6) * 4; ldsOff = 12288 + (wave - 6) * 2048; }
    const size_t rstep = (size_t)KS * 512;
    const bf16* g0 = gsrc + (size_t)grb * rstep + lane * 8;

    floatx4 accv[8][2], accr[8][2];
#pragma unroll
    for (int i = 0; i < 8; ++i)
#pragma unroll
        for (int j = 0; j < 2; ++j) {
            accv[i][j] = (floatx4){0.f, 0.f, 0.f, 0.f};
            accr[i][j] = (floatx4){0.f, 0.f, 0.f, 0.f};
        }

    // prologue: stage slice 0 into slot 0
    {
        bf16* dst = &lds[ldsOff];
        async_cp16(g0,             dst);
        async_cp16(g0 + rstep,     dst + 512);
        async_cp16(g0 + 2 * rstep, dst + 1024);
        async_cp16(g0 + 3 * rstep, dst + 1536);
        g0 += 512;
    }
    wait_vm<0>();
    barrier_pin();

#define VR_SLICE(q, DO_STAGE)                                                  \
    {                                                                          \
        const bf16* sb = &lds[((q) & 1) * 16384];                              \
        if (DO_STAGE) {                                                        \
            bf16* dst = &lds[(((q) + 1) & 1) * 16384 + ldsOff];                \
            async_cp16(g0,             dst);                                   \
            async_cp16(g0 + rstep,     dst + 512);                             \
            async_cp16(g0 + 2 * rstep, dst + 1024);                            \
            async_cp16(g0 + 3 * rstep, dst + 1536);                            \
            g0 += 512;                                                         \
        }                                                                      \
        bf16x8 xf[8], wvf[2], wrf[2];                                          \
        _Pragma("unroll")                                                      \
        for (int i = 0; i < 8; ++i)                                            \
            xf[i] = *(const bf16x8*)&sb[(xrb + i) * 512 + (lane << 3)];        \
        _Pragma("unroll")                                                      \
        for (int j = 0; j < 2; ++j) {                                          \
            wvf[j] = *(const bf16x8*)&sb[8192 + (wjb + j) * 512 + (lane << 3)];\
            wrf[j] = *(const bf16x8*)&sb[12288 + (wjb + j) * 512 + (lane << 3)];\
        }                                                                      \
        __builtin_amdgcn_s_setprio(1);                                         \
        _Pragma("unroll")                                                      \
        for (int i = 0; i < 8; ++i) {                                          \
            accv[i][0] = __builtin_amdgcn_mfma_f32_16x16x32_bf16(              \
                xf[i], wvf[0], accv[i][0], 0, 0, 0);                           \
            accv[i][1] = __builtin_amdgcn_mfma_f32_16x16x32_bf16(              \
                xf[i], wvf[1], accv[i][1], 0, 0, 0);                           \
            accr[i][0] = __builtin_amdgcn_mfma_f32_16x16x32_bf16(              \
                xf[i], wrf[0], accr[i][0], 0, 0, 0);                           \
            accr[i][1] = __builtin_amdgcn_mfma_f32_16x16x32_bf16(              \
                xf[i], wrf[1], accr[i][1], 0, 0, 0);                           \
        }                                                                      \
        __builtin_amdgcn_s_setprio(0);                                         \
        if (DO_STAGE) {                                                        \
            wait_vm<0>();                                                      \
            barrier_pin();                                                     \
        }                                                                      \
    }

    for (int q = 0; q < Q - 1; ++q) VR_SLICE(q, 1)
    VR_SLICE(Q - 1, 0)
#undef VR_SLICE

    // epilogue: bias reduce (16 partials per col) + sigmoid fuse + packet store
#pragma unroll
    for (int j = 0; j < 2; ++j) {
        const int col = n0 + wn + j * 16 + l16;
        float bvj = 0.f, brj = 0.f;
#pragma unroll
        for (int s = 0; s < 16; ++s) {
            bvj += pV[(size_t)s * N + col];
            brj += pR[(size_t)s * N + col];
        }
        const size_t cbase = (size_t)(col >> 5) * 512 +
                             (size_t)(((col >> 3) & 3) << 4) * 8 + (col & 7);
#pragma unroll
        for (int i = 0; i < 8; ++i) {
            const int rbg = ((m0 + wm) >> 4) + i;
            const size_t base = (size_t)rbg * (N >> 5) * 512 + cbase;
#pragma unroll
            for (int r = 0; r < 4; ++r) {
                const float vv = accv[i][j][r] + bvj;
                const float rr = accr[i][j][r] + brj;
                const float sg = 1.0f / (1.0f + __expf(-rr));
                RW[base + (size_t)(quad * 4 + r) * 8] = (bf16)(sg * vv);
            }
        }
    }
}

// ---------------------------------------------------------------------------
// gemm_o7: Of = A @ Bw^T, BM=256 BN=256, single-phase 4-slot counted-vmcnt
// pipeline (round-3 config, unchanged), fp32 row-major out.
// ---------------------------------------------------------------------------
__global__ __launch_bounds__(512, 2) void gemm_o7(
    const bf16* __restrict__ AB, const bf16* __restrict__ WB,
    float* __restrict__ Of, int M, int N, int K) {
    __shared__ __align__(16) bf16 lds[65536];

    const int bid    = blockIdx.x;
    const int xcd    = bid & 7;
    const int tt     = bid >> 3;
    const int mtPerX = (M >> 8) >> 3;            // 4
    const int mt     = xcd * mtPerX + (tt % mtPerX);
    const int nt     = tt / mtPerX;
    const int m0     = mt << 8;
    const int n0     = nt << 8;

    const int tid  = threadIdx.x;
    const int wave = tid >> 6;
    const int lane = tid & 63;
    const int quad = lane >> 4;
    const int l16  = lane & 15;
    const int wm   = (wave >> 2) << 7;
    const int wn   = (wave & 3) << 6;            // 0,64,128,192
    const int xrb  = (wave >> 2) << 3;
    const int wjb  = (wave & 3) << 2;
    const int KS   = K >> 5;
    const int Q    = K >> 5;

    const bf16* gsrc;
    int grb, ldsOff;
    if (wave < 4) { gsrc = AB; grb = (m0 >> 4) + wave * 4;       ldsOff = wave * 2048; }
    else          { gsrc = WB; grb = (n0 >> 4) + (wave - 4) * 4; ldsOff = 8192 + (wave - 4) * 2048; }
    const size_t rstep = (size_t)KS * 512;
    const bf16* g0 = gsrc + (size_t)grb * rstep + lane * 8;

    floatx4 acc[8][4];
#pragma unroll
    for (int i = 0; i < 8; ++i)
#pragma unroll
        for (int j = 0; j < 4; ++j) acc[i][j] = (floatx4){0.f, 0.f, 0.f, 0.f};

    for (int s = 0; s < 3; ++s) {
        bf16* dst = &lds[s * 16384 + ldsOff];
        async_cp16(g0,             dst);
        async_cp16(g0 + rstep,     dst + 512);
        async_cp16(g0 + 2 * rstep, dst + 1024);
        async_cp16(g0 + 3 * rstep, dst + 1536);
        g0 += 512;
    }
    wait_vm<8>();
    barrier_pin();

#define O_SLICE(q, DO_STAGE, VMODE)                                            \
    {                                                                          \
        const bf16* sb = &lds[((q) & 3) * 16384];                              \
        if (DO_STAGE) {                                                        \
            bf16* dst = &lds[(((q) + 3) & 3) * 16384 + ldsOff];                \
            async_cp16(g0,             dst);                                   \
            async_cp16(g0 + rstep,     dst + 512);                             \
            async_cp16(g0 + 2 * rstep, dst + 1024);                            \
            async_cp16(g0 + 3 * rstep, dst + 1536);                            \
            g0 += 512;                                                         \
        }                                                                      \
        bf16x8 xf[8], wf[4];                                                   \
        _Pragma("unroll")                                                      \
        for (int i = 0; i < 8; ++i)                                            \
            xf[i] = *(const bf16x8*)&sb[(xrb + i) * 512 + (lane << 3)];        \
        _Pragma("unroll")                                                      \
        for (int j = 0; j < 4; ++j)                                            \
            wf[j] = *(const bf16x8*)&sb[8192 + (wjb + j) * 512 + (lane << 3)]; \
        __builtin_amdgcn_s_setprio(1);                                         \
        _Pragma("unroll")                                                      \
        for (int i = 0; i < 8; ++i)                                            \
            _Pragma("unroll")                                                  \
            for (int j = 0; j < 4; ++j)                                        \
                acc[i][j] = __builtin_amdgcn_mfma_f32_16x16x32_bf16(           \
                    xf[i], wf[j], acc[i][j], 0, 0, 0);                         \
        __builtin_amdgcn_s_setprio(0);                                         \
        if ((VMODE) == 0) wait_vm<8>();                                        \
        else if ((VMODE) == 1) wait_vm<4>();                                   \
        else if ((VMODE) == 2) wait_vm<0>();                                   \
        barrier_pin();                                                         \
    }

    for (int q = 0; q < Q - 3; ++q) O_SLICE(q, 1, 0)
    O_SLICE(Q - 3, 0, 1)
    O_SLICE(Q - 2, 0, 2)
    O_SLICE(Q - 1, 0, 3)
#undef O_SLICE

#pragma unroll
    for (int i = 0; i < 8; ++i) {
        const int row0 = m0 + wm + i * 16 + quad * 4;
#pragma unroll
        for (int j = 0; j < 4; ++j) {
            const int col = n0 + wn + j * 16 + l16;
#pragma unroll
            for (int r = 0; r < 4; ++r)
                Of[(size_t)(row0 + r) * N + col] = acc[i][j][r];
        }
    }
}

extern "C" void kernel_launch(void* const* d_in, const int* in_sizes, int n_in,
                              void* d_out, int out_size, void* d_ws, size_t ws_size,
                              hipStream_t stream) {
    // inputs: 0:x 1:time_first 2:tmk 3:tmv 4:tmr 5:xx 6:aa 7:bb 8:pp
    //         9:w_key 10:w_value 11:w_rec 12:w_out   (k-GEMM dead: wkv == v)
    const int C = in_sizes[1];              // 2048
    const int M = in_sizes[0] / C;          // B*T = 8192
    const size_t MC = (size_t)M * C;
    const size_t CC = (size_t)C * C;

    const float* x   = (const float*)d_in[0];
    const float* tmv = (const float*)d_in[3];
    const float* tmr = (const float*)d_in[4];
    const float* xxp = (const float*)d_in[5];
    const float* wv  = (const float*)d_in[10];
    const float* wr  = (const float*)d_in[11];
    const float* wo  = (const float*)d_in[12];

    uint8_t* ws = (uint8_t*)d_ws;
    bf16* xb    = (bf16*)ws;
    bf16* rwkv  = (bf16*)(ws + MC * 2);
    bf16* wvb   = (bf16*)(ws + MC * 4);
    bf16* wrb   = (bf16*)(ws + MC * 4 + CC * 2);
    bf16* wob   = (bf16*)(ws + MC * 4 + CC * 4);
    float* pV   = (float*)(ws + MC * 4 + CC * 6);
    float* pR   = pV + 16 * (size_t)C;
    const size_t need = MC * 4 + CC * 6 + (size_t)C * 128;
    if (ws_size < need) return;

    dim3 gridP(C / 128, M / 16 + 3 * (C / 16));
    prep3<<<gridP, 256, 0, stream>>>(x, tmv, tmr, xxp, wv, wr, wo,
                                     xb, wvb, wrb, wob, pV, pR, C, M / 16);
    // rwkv = sigmoid(x@wr'^T + br) * (x@wv'^T + bv)
    gemm_vr7<<<(M / 256) * (C / 128), 512, 0, stream>>>(xb, wvb, wrb, pV, pR,
                                                        rwkv, M, C, C);
    // out = rwkv @ wo^T
    gemm_o7<<<(M / 256) * (C / 256), 512, 0, stream>>>(rwkv, wob, (float*)d_out,
                                                       M, C, C);
}

// Round 7
// 359.256 us; speedup vs baseline: 4.2934x; 4.2934x over previous
//
#include <hip/hip_runtime.h>
#include <hip/hip_bf16.h>
#include <cstdint>
#include <cstddef>

using bf16    = __bf16;
using bf16x8  = __attribute__((ext_vector_type(8))) __bf16;
using floatx4 = __attribute__((ext_vector_type(4))) float;

// Packet layout (all bf16 GEMM operands):
//   packet = 1024B = one (16-row x 32-k) block of row-major [R x K]
//   packet index = (row>>4)*(K>>5) + (k>>5)
//   element (row,k) at packet*512 + (((k>>3)&3)*16 + (row&15))*8 + (k&7)
// One global_load_lds(16B) per wave moves one packet; one ds_read_b128 per
// lane yields a full 16x32 MFMA fragment. Conflict-free both ways.
//
// ALGEBRA: xv = x*mv + (1-mv)*xx  =>  xv@Wv^T = x@(mv.*Wv)^T + bias_v.
// Both GEMMs of the v/r pair share A = bf16(x); mix folds into the weights.
// Bias partials [16][C] from prep3, summed in gemm_vr8 epilogue.
//
// SCHEDULE (v8): TLP via 2 blocks/CU.  Round-6 post-mortem: on this
// toolchain __launch_bounds__'s 2nd arg is MIN BLOCKS PER CU (CUDA
// semantics) -- (512,4) forced 32 waves/CU -> 64-VGPR cap -> all 128
// accumulator VGPRs spilled (WRITE_SIZE 33MB->4.4GB, MfmaUtil 4%).
// v8 = identical kernel with (512,2): VGPR cap 128 (body fits at ~112),
// 64 KiB LDS/block -> TWO independent blocks/CU.  One block's MFMA burst
// covers the other's ds_read burst + vmcnt(0) drain + barrier (m114).
// Per slice: stage q+1 into other slot, 12 ds_reads, 32 MFMA (setprio),
// vmcnt(0), barrier.
//   WAR: slot (q+1)&1 fully read before q-1's closing barrier.
//   RAW: vmcnt(0)+barrier at end of q -> slot q+1 ready for slice q+1.

__device__ __forceinline__ void async_cp16(const bf16* g, bf16* l) {
    __builtin_amdgcn_global_load_lds(
        (__attribute__((address_space(1))) void*)const_cast<bf16*>(g),
        (__attribute__((address_space(3))) void*)l,
        16, 0, 0);
}

template <int VM>
__device__ __forceinline__ void wait_vm() {
    if constexpr (VM == 8)      asm volatile("s_waitcnt vmcnt(8)" ::: "memory");
    else if constexpr (VM == 4) asm volatile("s_waitcnt vmcnt(4)" ::: "memory");
    else if constexpr (VM == 0) asm volatile("s_waitcnt vmcnt(0)" ::: "memory");
}

__device__ __forceinline__ void barrier_pin() {
    __builtin_amdgcn_s_barrier();
    __builtin_amdgcn_sched_barrier(0);
}

// ---------------------------------------------------------------------------
// prep3: yb < prepRows -> bf16(x) packets; else weight fold+convert:
//   wv' = mv.*Wv, wr' = mr.*Wr, wo' = Wo; bias partials [16][C] per array.
// ---------------------------------------------------------------------------
__global__ __launch_bounds__(256) void prep3(
    const float* __restrict__ x, const float* __restrict__ tmv,
    const float* __restrict__ tmr, const float* __restrict__ xxp,
    const float* __restrict__ wv, const float* __restrict__ wr,
    const float* __restrict__ wo, bf16* __restrict__ xb,
    bf16* __restrict__ wvb, bf16* __restrict__ wrb, bf16* __restrict__ wob,
    float* __restrict__ pV, float* __restrict__ pR,
    int C, int prepRows) {
    __shared__ float red[4][16];
    const int t  = threadIdx.x;
    const int p  = t >> 6, l = t & 63;
    const int c0 = blockIdx.x << 7;
    const int k  = c0 + (p << 5) + ((l >> 4) << 3);
    const int yb = blockIdx.y;
    const int C4 = C >> 4;

    if (yb < prepRows) {
        const int row = (yb << 4) + (l & 15);
        const float4* xi = (const float4*)&x[(size_t)row * C + k];
        const float4 a0 = xi[0], a1 = xi[1];
        const float xa[8] = {a0.x, a0.y, a0.z, a0.w, a1.x, a1.y, a1.z, a1.w};
        bf16x8 ov;
#pragma unroll
        for (int u = 0; u < 8; ++u) ov[u] = (bf16)xa[u];
        const size_t off = ((size_t)yb * (C >> 5) + (c0 >> 5) + p) * 512 + l * 8;
        *(bf16x8*)&xb[off] = ov;
    } else {
        int z = yb - prepRows;
        const float* wsrc; bf16* wdst; const float* sv = nullptr;
        float* bdst = nullptr; int mix = 1;
        if (z < C4)          { wsrc = wv; wdst = wvb; sv = tmv; bdst = pV; }
        else if (z < 2 * C4) { wsrc = wr; wdst = wrb; sv = tmr; bdst = pR; z -= C4; }
        else                 { wsrc = wo; wdst = wob; mix = 0; z -= 2 * C4; }
        const int row = (z << 4) + (l & 15);
        const float4* wi = (const float4*)&wsrc[(size_t)row * C + k];
        const float4 b0 = wi[0], b1 = wi[1];
        const float wa[8] = {b0.x, b0.y, b0.z, b0.w, b1.x, b1.y, b1.z, b1.w};
        bf16x8 ov;
        if (mix) {
            const float4 s0 = *(const float4*)&sv[k],  s1 = *(const float4*)&sv[k + 4];
            const float4 q0 = *(const float4*)&xxp[k], q1 = *(const float4*)&xxp[k + 4];
            const float sa[8] = {s0.x, s0.y, s0.z, s0.w, s1.x, s1.y, s1.z, s1.w};
            const float qa[8] = {q0.x, q0.y, q0.z, q0.w, q1.x, q1.y, q1.z, q1.w};
            float part = 0.f;
#pragma unroll
            for (int u = 0; u < 8; ++u) {
                part += (1.0f - sa[u]) * qa[u] * wa[u];
                ov[u] = (bf16)(wa[u] * sa[u]);
            }
            part += __shfl_xor(part, 16);
            part += __shfl_xor(part, 32);
            if (l < 16) red[p][l] = part;
            __syncthreads();
            if (t < 16) {
                const float s = red[0][t] + red[1][t] + red[2][t] + red[3][t];
                bdst[(size_t)(c0 >> 7) * C + (z << 4) + t] = s;
            }
        } else {
#pragma unroll
            for (int u = 0; u < 8; ++u) ov[u] = (bf16)wa[u];
        }
        const size_t off = ((size_t)z * (C >> 5) + (c0 >> 5) + p) * 512 + l * 8;
        *(bf16x8*)&wdst[off] = ov;
    }
}

// ---------------------------------------------------------------------------
// gemm_vr8: shared-A dual GEMM, BM=256 BN=128, 2-slot ring, 2 blocks/CU.
// LDS slot (16384 elems): X packets [0,16)*512, WV [16,24)*512, WR [24,32)*512.
// Waves 0-3 stage X, 4-5 WV, 6-7 WR.
// ---------------------------------------------------------------------------
__global__ __launch_bounds__(512, 2) void gemm_vr8(
    const bf16* __restrict__ XB, const bf16* __restrict__ WVB,
    const bf16* __restrict__ WRB, const float* __restrict__ pV,
    const float* __restrict__ pR, bf16* __restrict__ RW,
    int M, int N, int K) {
    __shared__ __align__(16) bf16 lds[32768];   // 64 KiB, 2 x 32KB slots

    const int bid    = blockIdx.x;
    const int xcd    = bid & 7;
    const int tt     = bid >> 3;
    const int mtPerX = (M >> 8) >> 3;            // 4
    const int mt     = xcd * mtPerX + (tt % mtPerX);
    const int nt     = tt / mtPerX;
    const int m0     = mt << 8;
    const int n0     = nt << 7;

    const int tid  = threadIdx.x;
    const int wave = tid >> 6;
    const int lane = tid & 63;
    const int quad = lane >> 4;
    const int l16  = lane & 15;
    const int wm   = (wave >> 2) << 7;           // 0 / 128
    const int wn   = (wave & 3) << 5;            // 0,32,64,96
    const int xrb  = (wave >> 2) << 3;
    const int wjb  = (wave & 3) << 1;
    const int KS   = K >> 5;
    const int Q    = K >> 5;

    const bf16* gsrc;
    int grb, ldsOff;
    if (wave < 4)      { gsrc = XB;  grb = (m0 >> 4) + wave * 4;       ldsOff = wave * 2048; }
    else if (wave < 6) { gsrc = WVB; grb = (n0 >> 4) + (wave - 4) * 4; ldsOff = 8192 + (wave - 4) * 2048; }
    else               { gsrc = WRB; grb = (n0 >> 4) + (wave - 6) * 4; ldsOff = 12288 + (wave - 6) * 2048; }
    const size_t rstep = (size_t)KS * 512;
    const bf16* g0 = gsrc + (size_t)grb * rstep + lane * 8;

    floatx4 accv[8][2], accr[8][2];
#pragma unroll
    for (int i = 0; i < 8; ++i)
#pragma unroll
        for (int j = 0; j < 2; ++j) {
            accv[i][j] = (floatx4){0.f, 0.f, 0.f, 0.f};
            accr[i][j] = (floatx4){0.f, 0.f, 0.f, 0.f};
        }

    // prologue: stage slice 0 into slot 0
    {
        bf16* dst = &lds[ldsOff];
        async_cp16(g0,             dst);
        async_cp16(g0 + rstep,     dst + 512);
        async_cp16(g0 + 2 * rstep, dst + 1024);
        async_cp16(g0 + 3 * rstep, dst + 1536);
        g0 += 512;
    }
    wait_vm<0>();
    barrier_pin();

#define VR_SLICE(q, DO_STAGE)                                                  \
    {                                                                          \
        const bf16* sb = &lds[((q) & 1) * 16384];                              \
        if (DO_STAGE) {                                                        \
            bf16* dst = &lds[(((q) + 1) & 1) * 16384 + ldsOff];                \
            async_cp16(g0,             dst);                                   \
            async_cp16(g0 + rstep,     dst + 512);                             \
            async_cp16(g0 + 2 * rstep, dst + 1024);                            \
            async_cp16(g0 + 3 * rstep, dst + 1536);                            \
            g0 += 512;                                                         \
        }                                                                      \
        bf16x8 xf[8], wvf[2], wrf[2];                                          \
        _Pragma("unroll")                                                      \
        for (int i = 0; i < 8; ++i)                                            \
            xf[i] = *(const bf16x8*)&sb[(xrb + i) * 512 + (lane << 3)];        \
        _Pragma("unroll")                                                      \
        for (int j = 0; j < 2; ++j) {                                          \
            wvf[j] = *(const bf16x8*)&sb[8192 + (wjb + j) * 512 + (lane << 3)];\
            wrf[j] = *(const bf16x8*)&sb[12288 + (wjb + j) * 512 + (lane << 3)];\
        }                                                                      \
        __builtin_amdgcn_s_setprio(1);                                         \
        _Pragma("unroll")                                                      \
        for (int i = 0; i < 8; ++i) {                                          \
            accv[i][0] = __builtin_amdgcn_mfma_f32_16x16x32_bf16(              \
                xf[i], wvf[0], accv[i][0], 0, 0, 0);                           \
            accv[i][1] = __builtin_amdgcn_mfma_f32_16x16x32_bf16(              \
                xf[i], wvf[1], accv[i][1], 0, 0, 0);                           \
            accr[i][0] = __builtin_amdgcn_mfma_f32_16x16x32_bf16(              \
                xf[i], wrf[0], accr[i][0], 0, 0, 0);                           \
            accr[i][1] = __builtin_amdgcn_mfma_f32_16x16x32_bf16(              \
                xf[i], wrf[1], accr[i][1], 0, 0, 0);                           \
        }                                                                      \
        __builtin_amdgcn_s_setprio(0);                                         \
        if (DO_STAGE) {                                                        \
            wait_vm<0>();                                                      \
            barrier_pin();                                                     \
        }                                                                      \
    }

    for (int q = 0; q < Q - 1; ++q) VR_SLICE(q, 1)
    VR_SLICE(Q - 1, 0)
#undef VR_SLICE

    // epilogue: bias reduce (16 partials per col) + sigmoid fuse + packet store
#pragma unroll
    for (int j = 0; j < 2; ++j) {
        const int col = n0 + wn + j * 16 + l16;
        float bvj = 0.f, brj = 0.f;
#pragma unroll
        for (int s = 0; s < 16; ++s) {
            bvj += pV[(size_t)s * N + col];
            brj += pR[(size_t)s * N + col];
        }
        const size_t cbase = (size_t)(col >> 5) * 512 +
                             (size_t)(((col >> 3) & 3) << 4) * 8 + (col & 7);
#pragma unroll
        for (int i = 0; i < 8; ++i) {
            const int rbg = ((m0 + wm) >> 4) + i;
            const size_t base = (size_t)rbg * (N >> 5) * 512 + cbase;
#pragma unroll
            for (int r = 0; r < 4; ++r) {
                const float vv = accv[i][j][r] + bvj;
                const float rr = accr[i][j][r] + brj;
                const float sg = 1.0f / (1.0f + __expf(-rr));
                RW[base + (size_t)(quad * 4 + r) * 8] = (bf16)(sg * vv);
            }
        }
    }
}

// ---------------------------------------------------------------------------
// gemm_o8: Of = A @ Bw^T, BM=256 BN=256, single-phase 4-slot counted-vmcnt
// pipeline (round-3 config, unchanged), fp32 row-major out.
// ---------------------------------------------------------------------------
__global__ __launch_bounds__(512, 1) void gemm_o8(
    const bf16* __restrict__ AB, const bf16* __restrict__ WB,
    float* __restrict__ Of, int M, int N, int K) {
    __shared__ __align__(16) bf16 lds[65536];

    const int bid    = blockIdx.x;
    const int xcd    = bid & 7;
    const int tt     = bid >> 3;
    const int mtPerX = (M >> 8) >> 3;            // 4
    const int mt     = xcd * mtPerX + (tt % mtPerX);
    const int nt     = tt / mtPerX;
    const int m0     = mt << 8;
    const int n0     = nt << 8;

    const int tid  = threadIdx.x;
    const int wave = tid >> 6;
    const int lane = tid & 63;
    const int quad = lane >> 4;
    const int l16  = lane & 15;
    const int wm   = (wave >> 2) << 7;
    const int wn   = (wave & 3) << 6;            // 0,64,128,192
    const int xrb  = (wave >> 2) << 3;
    const int wjb  = (wave & 3) << 2;
    const int KS   = K >> 5;
    const int Q    = K >> 5;

    const bf16* gsrc;
    int grb, ldsOff;
    if (wave < 4) { gsrc = AB; grb = (m0 >> 4) + wave * 4;       ldsOff = wave * 2048; }
    else          { gsrc = WB; grb = (n0 >> 4) + (wave - 4) * 4; ldsOff = 8192 + (wave - 4) * 2048; }
    const size_t rstep = (size_t)KS * 512;
    const bf16* g0 = gsrc + (size_t)grb * rstep + lane * 8;

    floatx4 acc[8][4];
#pragma unroll
    for (int i = 0; i < 8; ++i)
#pragma unroll
        for (int j = 0; j < 4; ++j) acc[i][j] = (floatx4){0.f, 0.f, 0.f, 0.f};

    for (int s = 0; s < 3; ++s) {
        bf16* dst = &lds[s * 16384 + ldsOff];
        async_cp16(g0,             dst);
        async_cp16(g0 + rstep,     dst + 512);
        async_cp16(g0 + 2 * rstep, dst + 1024);
        async_cp16(g0 + 3 * rstep, dst + 1536);
        g0 += 512;
    }
    wait_vm<8>();
    barrier_pin();

#define O_SLICE(q, DO_STAGE, VMODE)                                            \
    {                                                                          \
        const bf16* sb = &lds[((q) & 3) * 16384];                              \
        if (DO_STAGE) {                                                        \
            bf16* dst = &lds[(((q) + 3) & 3) * 16384 + ldsOff];                \
            async_cp16(g0,             dst);                                   \
            async_cp16(g0 + rstep,     dst + 512);                             \
            async_cp16(g0 + 2 * rstep, dst + 1024);                            \
            async_cp16(g0 + 3 * rstep, dst + 1536);                            \
            g0 += 512;                                                         \
        }                                                                      \
        bf16x8 xf[8], wf[4];                                                   \
        _Pragma("unroll")                                                      \
        for (int i = 0; i < 8; ++i)                                            \
            xf[i] = *(const bf16x8*)&sb[(xrb + i) * 512 + (lane << 3)];        \
        _Pragma("unroll")                                                      \
        for (int j = 0; j < 4; ++j)                                            \
            wf[j] = *(const bf16x8*)&sb[8192 + (wjb + j) * 512 + (lane << 3)]; \
        __builtin_amdgcn_s_setprio(1);                                         \
        _Pragma("unroll")                                                      \
        for (int i = 0; i < 8; ++i)                                            \
            _Pragma("unroll")                                                  \
            for (int j = 0; j < 4; ++j)                                        \
                acc[i][j] = __builtin_amdgcn_mfma_f32_16x16x32_bf16(           \
                    xf[i], wf[j], acc[i][j], 0, 0, 0);                         \
        __builtin_amdgcn_s_setprio(0);                                         \
        if ((VMODE) == 0) wait_vm<8>();                                        \
        else if ((VMODE) == 1) wait_vm<4>();                                   \
        else if ((VMODE) == 2) wait_vm<0>();                                   \
        barrier_pin();                                                         \
    }

    for (int q = 0; q < Q - 3; ++q) O_SLICE(q, 1, 0)
    O_SLICE(Q - 3, 0, 1)
    O_SLICE(Q - 2, 0, 2)
    O_SLICE(Q - 1, 0, 3)
#undef O_SLICE

#pragma unroll
    for (int i = 0; i < 8; ++i) {
        const int row0 = m0 + wm + i * 16 + quad * 4;
#pragma unroll
        for (int j = 0; j < 4; ++j) {
            const int col = n0 + wn + j * 16 + l16;
#pragma unroll
            for (int r = 0; r < 4; ++r)
                Of[(size_t)(row0 + r) * N + col] = acc[i][j][r];
        }
    }
}

extern "C" void kernel_launch(void* const* d_in, const int* in_sizes, int n_in,
                              void* d_out, int out_size, void* d_ws, size_t ws_size,
                              hipStream_t stream) {
    // inputs: 0:x 1:time_first 2:tmk 3:tmv 4:tmr 5:xx 6:aa 7:bb 8:pp
    //         9:w_key 10:w_value 11:w_rec 12:w_out   (k-GEMM dead: wkv == v)
    const int C = in_sizes[1];              // 2048
    const int M = in_sizes[0] / C;          // B*T = 8192
    const size_t MC = (size_t)M * C;
    const size_t CC = (size_t)C * C;

    const float* x   = (const float*)d_in[0];
    const float* tmv = (const float*)d_in[3];
    const float* tmr = (const float*)d_in[4];
    const float* xxp = (const float*)d_in[5];
    const float* wv  = (const float*)d_in[10];
    const float* wr  = (const float*)d_in[11];
    const float* wo  = (const float*)d_in[12];

    uint8_t* ws = (uint8_t*)d_ws;
    bf16* xb    = (bf16*)ws;
    bf16* rwkv  = (bf16*)(ws + MC * 2);
    bf16* wvb   = (bf16*)(ws + MC * 4);
    bf16* wrb   = (bf16*)(ws + MC * 4 + CC * 2);
    bf16* wob   = (bf16*)(ws + MC * 4 + CC * 4);
    float* pV   = (float*)(ws + MC * 4 + CC * 6);
    float* pR   = pV + 16 * (size_t)C;
    const size_t need = MC * 4 + CC * 6 + (size_t)C * 128;
    if (ws_size < need) return;

    dim3 gridP(C / 128, M / 16 + 3 * (C / 16));
    prep3<<<gridP, 256, 0, stream>>>(x, tmv, tmr, xxp, wv, wr, wo,
                                     xb, wvb, wrb, wob, pV, pR, C, M / 16);
    // rwkv = sigmoid(x@wr'^T + br) * (x@wv'^T + bv)
    gemm_vr8<<<(M / 256) * (C / 128), 512, 0, stream>>>(xb, wvb, wrb, pV, pR,
                                                        rwkv, M, C, C);
    // out = rwkv @ wo^T
    gemm_o8<<<(M / 256) * (C / 256), 512, 0, stream>>>(rwkv, wob, (float*)d_out,
                                                       M, C, C);
}

// Round 8
// 345.919 us; speedup vs baseline: 4.4590x; 1.0386x over previous
//
#include <hip/hip_runtime.h>
#include <hip/hip_bf16.h>
#include <cstdint>
#include <cstddef>

using bf16    = __bf16;
using bf16x8  = __attribute__((ext_vector_type(8))) __bf16;
using floatx4 = __attribute__((ext_vector_type(4))) float;

// Packet layout (all bf16 GEMM operands):
//   packet = 1024B = one (16-row x 32-k) block of row-major [R x K]
//   packet index = (row>>4)*(K>>5) + (k>>5)
//   element (row,k) at packet*512 + (((k>>3)&3)*16 + (row&15))*8 + (k&7)
// One global_load_lds(16B) per wave moves one packet; one ds_read_b128 per
// lane yields a full 16x32 MFMA fragment. Conflict-free both ways.
//
// ALGEBRA: xv = x*mv + (1-mv)*xx  =>  xv@Wv^T = x@(mv.*Wv)^T + bias_v.
// Both GEMMs of the v/r pair share A = bf16(x); mix folds into the weights.
// Bias partials [16][C] from prep3, summed in gemm_vr9 epilogue.
//
// SCHEDULE (v9) = v6 structure at the CORRECT register cap.
// Round-7 post-mortem: acc lives in AGPRs (unified file) -> true per-wave
// usage ~= VGPR_Count + 128.  Occupancy is pinned at 1 block / 8 waves / CU
// (2 waves/SIMD) for ANY decent tile, so the register budget is 256/wave.
// v6's fenced one-slice-ahead prefetch (X AND W into alternate reg sets,
// sched_barrier(0) fence before the MFMA cluster) is exactly the m201
// trick -- operands are read a FULL SLICE before use, so the MFMA cluster
// has zero lgkm wait and the CU's DS burst drains under the previous MFMA
// window -- but v6 ran it under launch_bounds(512,2) (cap 128) and spilled
// (WRITE_SIZE +2MB).  v9 = v6 with launch_bounds(512,1): cap 256, budget
// acc 128 + X-dbuf 64 + W-dbuf 32 + addr ~20 ~= 240.  No other change.
// Ledger (4 stages/slice): entering slice q, outstanding = q+2's stages.
//   Issue q+3 -> 8 outstanding; end vmcnt(4) retires q+2.  Slot q+1 was
//   confirmed at end of q-1, published by its barrier -> prefetch RAW ok.
//   Stage targets slot (q+3)&3 == (q-1)&3 (consumed through slice q-1,
//   reads retired before its closing barrier) -> WAR ok.
//   Tail: vm4 thru Q-4, vm0 at Q-3, none after; Q-1 no prefetch.

__device__ __forceinline__ void async_cp16(const bf16* g, bf16* l) {
    __builtin_amdgcn_global_load_lds(
        (__attribute__((address_space(1))) void*)const_cast<bf16*>(g),
        (__attribute__((address_space(3))) void*)l,
        16, 0, 0);
}

template <int VM>
__device__ __forceinline__ void wait_vm() {
    if constexpr (VM == 4) asm volatile("s_waitcnt vmcnt(4)" ::: "memory");
    else if constexpr (VM == 0) asm volatile("s_waitcnt vmcnt(0)" ::: "memory");
}

__device__ __forceinline__ void barrier_pin() {
    __builtin_amdgcn_s_barrier();
    __builtin_amdgcn_sched_barrier(0);
}

// ---------------------------------------------------------------------------
// prep3: yb < prepRows -> bf16(x) packets; else weight fold+convert:
//   wv' = mv.*Wv, wr' = mr.*Wr, wo' = Wo; bias partials [16][C] per array.
// ---------------------------------------------------------------------------
__global__ __launch_bounds__(256) void prep3(
    const float* __restrict__ x, const float* __restrict__ tmv,
    const float* __restrict__ tmr, const float* __restrict__ xxp,
    const float* __restrict__ wv, const float* __restrict__ wr,
    const float* __restrict__ wo, bf16* __restrict__ xb,
    bf16* __restrict__ wvb, bf16* __restrict__ wrb, bf16* __restrict__ wob,
    float* __restrict__ pV, float* __restrict__ pR,
    int C, int prepRows) {
    __shared__ float red[4][16];
    const int t  = threadIdx.x;
    const int p  = t >> 6, l = t & 63;
    const int c0 = blockIdx.x << 7;
    const int k  = c0 + (p << 5) + ((l >> 4) << 3);
    const int yb = blockIdx.y;
    const int C4 = C >> 4;

    if (yb < prepRows) {
        const int row = (yb << 4) + (l & 15);
        const float4* xi = (const float4*)&x[(size_t)row * C + k];
        const float4 a0 = xi[0], a1 = xi[1];
        const float xa[8] = {a0.x, a0.y, a0.z, a0.w, a1.x, a1.y, a1.z, a1.w};
        bf16x8 ov;
#pragma unroll
        for (int u = 0; u < 8; ++u) ov[u] = (bf16)xa[u];
        const size_t off = ((size_t)yb * (C >> 5) + (c0 >> 5) + p) * 512 + l * 8;
        *(bf16x8*)&xb[off] = ov;
    } else {
        int z = yb - prepRows;
        const float* wsrc; bf16* wdst; const float* sv = nullptr;
        float* bdst = nullptr; int mix = 1;
        if (z < C4)          { wsrc = wv; wdst = wvb; sv = tmv; bdst = pV; }
        else if (z < 2 * C4) { wsrc = wr; wdst = wrb; sv = tmr; bdst = pR; z -= C4; }
        else                 { wsrc = wo; wdst = wob; mix = 0; z -= 2 * C4; }
        const int row = (z << 4) + (l & 15);
        const float4* wi = (const float4*)&wsrc[(size_t)row * C + k];
        const float4 b0 = wi[0], b1 = wi[1];
        const float wa[8] = {b0.x, b0.y, b0.z, b0.w, b1.x, b1.y, b1.z, b1.w};
        bf16x8 ov;
        if (mix) {
            const float4 s0 = *(const float4*)&sv[k],  s1 = *(const float4*)&sv[k + 4];
            const float4 q0 = *(const float4*)&xxp[k], q1 = *(const float4*)&xxp[k + 4];
            const float sa[8] = {s0.x, s0.y, s0.z, s0.w, s1.x, s1.y, s1.z, s1.w};
            const float qa[8] = {q0.x, q0.y, q0.z, q0.w, q1.x, q1.y, q1.z, q1.w};
            float part = 0.f;
#pragma unroll
            for (int u = 0; u < 8; ++u) {
                part += (1.0f - sa[u]) * qa[u] * wa[u];
                ov[u] = (bf16)(wa[u] * sa[u]);
            }
            part += __shfl_xor(part, 16);
            part += __shfl_xor(part, 32);
            if (l < 16) red[p][l] = part;
            __syncthreads();
            if (t < 16) {
                const float s = red[0][t] + red[1][t] + red[2][t] + red[3][t];
                bdst[(size_t)(c0 >> 7) * C + (z << 4) + t] = s;
            }
        } else {
#pragma unroll
            for (int u = 0; u < 8; ++u) ov[u] = (bf16)wa[u];
        }
        const size_t off = ((size_t)z * (C >> 5) + (c0 >> 5) + p) * 512 + l * 8;
        *(bf16x8*)&wdst[off] = ov;
    }
}

// ---------------------------------------------------------------------------
// gemm_vr9: shared-A dual GEMM, BM=256 BN=128, fenced prefetch pipeline,
// register cap 256 (1 block/CU is the true occupancy; acc in AGPRs).
// LDS slot (16384 elems): X packets [0,16)*512, WV [16,24)*512, WR [24,32)*512.
// Waves 0-3 stage X, 4-5 WV, 6-7 WR.
// ---------------------------------------------------------------------------
__global__ __launch_bounds__(512, 1) void gemm_vr9(
    const bf16* __restrict__ XB, const bf16* __restrict__ WVB,
    const bf16* __restrict__ WRB, const float* __restrict__ pV,
    const float* __restrict__ pR, bf16* __restrict__ RW,
    int M, int N, int K) {
    __shared__ __align__(16) bf16 lds[65536];   // 128 KiB, 4 x 32KB slots

    const int bid    = blockIdx.x;
    const int xcd    = bid & 7;
    const int tt     = bid >> 3;
    const int mtPerX = (M >> 8) >> 3;            // 4
    const int mt     = xcd * mtPerX + (tt % mtPerX);
    const int nt     = tt / mtPerX;
    const int m0     = mt << 8;
    const int n0     = nt << 7;

    const int tid  = threadIdx.x;
    const int wave = tid >> 6;
    const int lane = tid & 63;
    const int quad = lane >> 4;
    const int l16  = lane & 15;
    const int wm   = (wave >> 2) << 7;           // 0 / 128
    const int wn   = (wave & 3) << 5;            // 0,32,64,96
    const int xrb  = (wave >> 2) << 3;
    const int wjb  = (wave & 3) << 1;
    const int KS   = K >> 5;
    const int Q    = K >> 5;                     // 64 (even, >= 8)

    const bf16* gsrc;
    int grb, ldsOff;
    if (wave < 4)      { gsrc = XB;  grb = (m0 >> 4) + wave * 4;       ldsOff = wave * 2048; }
    else if (wave < 6) { gsrc = WVB; grb = (n0 >> 4) + (wave - 4) * 4; ldsOff = 8192 + (wave - 4) * 2048; }
    else               { gsrc = WRB; grb = (n0 >> 4) + (wave - 6) * 4; ldsOff = 12288 + (wave - 6) * 2048; }
    const size_t rstep = (size_t)KS * 512;
    const bf16* g0 = gsrc + (size_t)grb * rstep + lane * 8;

    floatx4 accv[8][2], accr[8][2];
#pragma unroll
    for (int i = 0; i < 8; ++i)
#pragma unroll
        for (int j = 0; j < 2; ++j) {
            accv[i][j] = (floatx4){0.f, 0.f, 0.f, 0.f};
            accr[i][j] = (floatx4){0.f, 0.f, 0.f, 0.f};
        }

    for (int s = 0; s < 3; ++s) {
        bf16* dst = &lds[s * 16384 + ldsOff];
        async_cp16(g0,             dst);
        async_cp16(g0 + rstep,     dst + 512);
        async_cp16(g0 + 2 * rstep, dst + 1024);
        async_cp16(g0 + 3 * rstep, dst + 1536);
        g0 += 512;
    }
    wait_vm<4>();        // slices 0 and 1 landed
    barrier_pin();

    bf16x8 xfA[8], xfB[8], wvA[2], wvB[2], wrA[2], wrB[2];
#pragma unroll
    for (int i = 0; i < 8; ++i)
        xfA[i] = *(const bf16x8*)&lds[(xrb + i) * 512 + (lane << 3)];
#pragma unroll
    for (int j = 0; j < 2; ++j) {
        wvA[j] = *(const bf16x8*)&lds[8192 + (wjb + j) * 512 + (lane << 3)];
        wrA[j] = *(const bf16x8*)&lds[12288 + (wjb + j) * 512 + (lane << 3)];
    }

#define VR_SLICE(q, XI, WVI, WRI, XO, WVO, WRO, DO_STAGE, VMODE, DO_PF, DO_BAR)\
    {                                                                          \
        const bf16* sbn = &lds[(((q) + 1) & 3) * 16384];                       \
        if (DO_STAGE) {                                                        \
            bf16* dst = &lds[(((q) + 3) & 3) * 16384 + ldsOff];                \
            async_cp16(g0,             dst);                                   \
            async_cp16(g0 + rstep,     dst + 512);                             \
            async_cp16(g0 + 2 * rstep, dst + 1024);                            \
            async_cp16(g0 + 3 * rstep, dst + 1536);                            \
            g0 += 512;                                                         \
        }                                                                      \
        if (DO_PF) {                                                           \
            _Pragma("unroll")                                                  \
            for (int i = 0; i < 8; ++i)                                        \
                XO[i] = *(const bf16x8*)&sbn[(xrb + i) * 512 + (lane << 3)];   \
            _Pragma("unroll")                                                  \
            for (int j = 0; j < 2; ++j) {                                      \
                WVO[j] = *(const bf16x8*)&sbn[8192 + (wjb + j) * 512 + (lane << 3)];  \
                WRO[j] = *(const bf16x8*)&sbn[12288 + (wjb + j) * 512 + (lane << 3)]; \
            }                                                                  \
        }                                                                      \
        __builtin_amdgcn_sched_barrier(0);                                     \
        __builtin_amdgcn_s_setprio(1);                                         \
        _Pragma("unroll")                                                      \
        for (int i = 0; i < 8; ++i) {                                          \
            accv[i][0] = __builtin_amdgcn_mfma_f32_16x16x32_bf16(              \
                XI[i], WVI[0], accv[i][0], 0, 0, 0);                           \
            accv[i][1] = __builtin_amdgcn_mfma_f32_16x16x32_bf16(              \
                XI[i], WVI[1], accv[i][1], 0, 0, 0);                           \
            accr[i][0] = __builtin_amdgcn_mfma_f32_16x16x32_bf16(              \
                XI[i], WRI[0], accr[i][0], 0, 0, 0);                           \
            accr[i][1] = __builtin_amdgcn_mfma_f32_16x16x32_bf16(              \
                XI[i], WRI[1], accr[i][1], 0, 0, 0);                           \
        }                                                                      \
        __builtin_amdgcn_s_setprio(0);                                         \
        if ((VMODE) == 0) wait_vm<4>();                                        \
        else if ((VMODE) == 1) wait_vm<0>();                                   \
        if (DO_BAR) barrier_pin();                                             \
    }

    for (int q = 0; q < Q - 4; q += 2) {
        VR_SLICE(q,     xfA, wvA, wrA, xfB, wvB, wrB, 1, 0, 1, 1)
        VR_SLICE(q + 1, xfB, wvB, wrB, xfA, wvA, wrA, 1, 0, 1, 1)
    }
    VR_SLICE(Q - 4, xfA, wvA, wrA, xfB, wvB, wrB, 1, 0, 1, 1)
    VR_SLICE(Q - 3, xfB, wvB, wrB, xfA, wvA, wrA, 0, 1, 1, 1)
    VR_SLICE(Q - 2, xfA, wvA, wrA, xfB, wvB, wrB, 0, 2, 1, 1)
    VR_SLICE(Q - 1, xfB, wvB, wrB, xfA, wvA, wrA, 0, 2, 0, 0)
#undef VR_SLICE

    // epilogue: bias reduce (16 partials per col) + sigmoid fuse + packet store
#pragma unroll
    for (int j = 0; j < 2; ++j) {
        const int col = n0 + wn + j * 16 + l16;
        float bvj = 0.f, brj = 0.f;
#pragma unroll
        for (int s = 0; s < 16; ++s) {
            bvj += pV[(size_t)s * N + col];
            brj += pR[(size_t)s * N + col];
        }
        const size_t cbase = (size_t)(col >> 5) * 512 +
                             (size_t)(((col >> 3) & 3) << 4) * 8 + (col & 7);
#pragma unroll
        for (int i = 0; i < 8; ++i) {
            const int rbg = ((m0 + wm) >> 4) + i;
            const size_t base = (size_t)rbg * (N >> 5) * 512 + cbase;
#pragma unroll
            for (int r = 0; r < 4; ++r) {
                const float vv = accv[i][j][r] + bvj;
                const float rr = accr[i][j][r] + brj;
                const float sg = 1.0f / (1.0f + __expf(-rr));
                RW[base + (size_t)(quad * 4 + r) * 8] = (bf16)(sg * vv);
            }
        }
    }
}

// ---------------------------------------------------------------------------
// gemm_o9: Of = A @ Bw^T, BM=256 BN=256, fenced prefetch pipeline,
// register cap 256, fp32 row-major out.
// LDS slot: A packets [0,16)*512, W packets [16,32)*512.
// ---------------------------------------------------------------------------
__global__ __launch_bounds__(512, 1) void gemm_o9(
    const bf16* __restrict__ AB, const bf16* __restrict__ WB,
    float* __restrict__ Of, int M, int N, int K) {
    __shared__ __align__(16) bf16 lds[65536];

    const int bid    = blockIdx.x;
    const int xcd    = bid & 7;
    const int tt     = bid >> 3;
    const int mtPerX = (M >> 8) >> 3;            // 4
    const int mt     = xcd * mtPerX + (tt % mtPerX);
    const int nt     = tt / mtPerX;
    const int m0     = mt << 8;
    const int n0     = nt << 8;

    const int tid  = threadIdx.x;
    const int wave = tid >> 6;
    const int lane = tid & 63;
    const int quad = lane >> 4;
    const int l16  = lane & 15;
    const int wm   = (wave >> 2) << 7;
    const int wn   = (wave & 3) << 6;            // 0,64,128,192
    const int xrb  = (wave >> 2) << 3;
    const int wjb  = (wave & 3) << 2;
    const int KS   = K >> 5;
    const int Q    = K >> 5;

    const bf16* gsrc;
    int grb, ldsOff;
    if (wave < 4) { gsrc = AB; grb = (m0 >> 4) + wave * 4;       ldsOff = wave * 2048; }
    else          { gsrc = WB; grb = (n0 >> 4) + (wave - 4) * 4; ldsOff = 8192 + (wave - 4) * 2048; }
    const size_t rstep = (size_t)KS * 512;
    const bf16* g0 = gsrc + (size_t)grb * rstep + lane * 8;

    floatx4 acc[8][4];
#pragma unroll
    for (int i = 0; i < 8; ++i)
#pragma unroll
        for (int j = 0; j < 4; ++j) acc[i][j] = (floatx4){0.f, 0.f, 0.f, 0.f};

    for (int s = 0; s < 3; ++s) {
        bf16* dst = &lds[s * 16384 + ldsOff];
        async_cp16(g0,             dst);
        async_cp16(g0 + rstep,     dst + 512);
        async_cp16(g0 + 2 * rstep, dst + 1024);
        async_cp16(g0 + 3 * rstep, dst + 1536);
        g0 += 512;
    }
    wait_vm<4>();
    barrier_pin();

    bf16x8 xfA[8], xfB[8], wfA[4], wfB[4];
#pragma unroll
    for (int i = 0; i < 8; ++i)
        xfA[i] = *(const bf16x8*)&lds[(xrb + i) * 512 + (lane << 3)];
#pragma unroll
    for (int j = 0; j < 4; ++j)
        wfA[j] = *(const bf16x8*)&lds[8192 + (wjb + j) * 512 + (lane << 3)];

#define O_SLICE(q, XI, WI, XO, WO, DO_STAGE, VMODE, DO_PF, DO_BAR)             \
    {                                                                          \
        const bf16* sbn = &lds[(((q) + 1) & 3) * 16384];                       \
        if (DO_STAGE) {                                                        \
            bf16* dst = &lds[(((q) + 3) & 3) * 16384 + ldsOff];                \
            async_cp16(g0,             dst);                                   \
            async_cp16(g0 + rstep,     dst + 512);                             \
            async_cp16(g0 + 2 * rstep, dst + 1024);                            \
            async_cp16(g0 + 3 * rstep, dst + 1536);                            \
            g0 += 512;                                                         \
        }                                                                      \
        if (DO_PF) {                                                           \
            _Pragma("unroll")                                                  \
            for (int i = 0; i < 8; ++i)                                        \
                XO[i] = *(const bf16x8*)&sbn[(xrb + i) * 512 + (lane << 3)];   \
            _Pragma("unroll")                                                  \
            for (int j = 0; j < 4; ++j)                                        \
                WO[j] = *(const bf16x8*)&sbn[8192 + (wjb + j) * 512 + (lane << 3)]; \
        }                                                                      \
        __builtin_amdgcn_sched_barrier(0);                                     \
        __builtin_amdgcn_s_setprio(1);                                         \
        _Pragma("unroll")                                                      \
        for (int i = 0; i < 8; ++i)                                            \
            _Pragma("unroll")                                                  \
            for (int j = 0; j < 4; ++j)                                        \
                acc[i][j] = __builtin_amdgcn_mfma_f32_16x16x32_bf16(           \
                    XI[i], WI[j], acc[i][j], 0, 0, 0);                         \
        __builtin_amdgcn_s_setprio(0);                                         \
        if ((VMODE) == 0) wait_vm<4>();                                        \
        else if ((VMODE) == 1) wait_vm<0>();                                   \
        if (DO_BAR) barrier_pin();                                             \
    }

    for (int q = 0; q < Q - 4; q += 2) {
        O_SLICE(q,     xfA, wfA, xfB, wfB, 1, 0, 1, 1)
        O_SLICE(q + 1, xfB, wfB, xfA, wfA, 1, 0, 1, 1)
    }
    O_SLICE(Q - 4, xfA, wfA, xfB, wfB, 1, 0, 1, 1)
    O_SLICE(Q - 3, xfB, wfB, xfA, wfA, 0, 1, 1, 1)
    O_SLICE(Q - 2, xfA, wfA, xfB, wfB, 0, 2, 1, 1)
    O_SLICE(Q - 1, xfB, wfB, xfA, wfA, 0, 2, 0, 0)
#undef O_SLICE

#pragma unroll
    for (int i = 0; i < 8; ++i) {
        const int row0 = m0 + wm + i * 16 + quad * 4;
#pragma unroll
        for (int j = 0; j < 4; ++j) {
            const int col = n0 + wn + j * 16 + l16;
#pragma unroll
            for (int r = 0; r < 4; ++r)
                Of[(size_t)(row0 + r) * N + col] = acc[i][j][r];
        }
    }
}

extern "C" void kernel_launch(void* const* d_in, const int* in_sizes, int n_in,
                              void* d_out, int out_size, void* d_ws, size_t ws_size,
                              hipStream_t stream) {
    // inputs: 0:x 1:time_first 2:tmk 3:tmv 4:tmr 5:xx 6:aa 7:bb 8:pp
    //         9:w_key 10:w_value 11:w_rec 12:w_out   (k-GEMM dead: wkv == v)
    const int C = in_sizes[1];              // 2048
    const int M = in_sizes[0] / C;          // B*T = 8192
    const size_t MC = (size_t)M * C;
    const size_t CC = (size_t)C * C;

    const float* x   = (const float*)d_in[0];
    const float* tmv = (const float*)d_in[3];
    const float* tmr = (const float*)d_in[4];
    const float* xxp = (const float*)d_in[5];
    const float* wv  = (const float*)d_in[10];
    const float* wr  = (const float*)d_in[11];
    const float* wo  = (const float*)d_in[12];

    uint8_t* ws = (uint8_t*)d_ws;
    bf16* xb    = (bf16*)ws;
    bf16* rwkv  = (bf16*)(ws + MC * 2);
    bf16* wvb   = (bf16*)(ws + MC * 4);
    bf16* wrb   = (bf16*)(ws + MC * 4 + CC * 2);
    bf16* wob   = (bf16*)(ws + MC * 4 + CC * 4);
    float* pV   = (float*)(ws + MC * 4 + CC * 6);
    float* pR   = pV + 16 * (size_t)C;
    const size_t need = MC * 4 + CC * 6 + (size_t)C * 128;
    if (ws_size < need) return;

    dim3 gridP(C / 128, M / 16 + 3 * (C / 16));
    prep3<<<gridP, 256, 0, stream>>>(x, tmv, tmr, xxp, wv, wr, wo,
                                     xb, wvb, wrb, wob, pV, pR, C, M / 16);
    // rwkv = sigmoid(x@wr'^T + br) * (x@wv'^T + bv)
    gemm_vr9<<<(M / 256) * (C / 128), 512, 0, stream>>>(xb, wvb, wrb, pV, pR,
                                                        rwkv, M, C, C);
    // out = rwkv @ wo^T
    gemm_o9<<<(M / 256) * (C / 256), 512, 0, stream>>>(rwkv, wob, (float*)d_out,
                                                       M, C, C);
}